// Round 6
// baseline (986.954 us; speedup 1.0000x reference)
//
#include <hip/hip_runtime.h>
#include <hip/hip_bf16.h>

typedef float f32x4 __attribute__((ext_vector_type(4)));
typedef short s16x8 __attribute__((ext_vector_type(8)));

__device__ __forceinline__ float pv_sigm(float x){ return 1.0f/(1.0f + __expf(-x)); }
__device__ __forceinline__ float pv_tanh(float x){ float e = __expf(2.0f*x); return 1.0f - 2.0f/(e + 1.0f); }

__device__ __forceinline__ unsigned short pv_f2b(float x){
  union { float f; unsigned u; } c; c.f = x;
  unsigned r = (c.u + 0x7fffu + ((c.u >> 16) & 1u)) >> 16;
  return (unsigned short)r;
}
__device__ __forceinline__ unsigned pv_pack2(float a, float b){
  return ((unsigned)pv_f2b(b) << 16) | (unsigned)pv_f2b(a);
}
__device__ __forceinline__ float pv_lo(unsigned u){
  union { unsigned u; float f; } c; c.u = u << 16; return c.f;
}
__device__ __forceinline__ float pv_hi(unsigned u){
  union { unsigned u; float f; } c; c.u = u & 0xffff0000u; return c.f;
}

// manual OCP e4m3fn encode (RNE); valid for |x| < 448
__device__ __forceinline__ unsigned char pv_fp8(float x){
  union { float f; unsigned u; } c; c.f = x;
  unsigned s = (c.u >> 24) & 0x80u;
  unsigned au = c.u & 0x7fffffffu;
  if (au == 0u) return (unsigned char)s;
  int ex = (int)(au >> 23) - 127;
  if (ex < -6) ex = -6;
  union { unsigned u; float f; } iv; iv.u = (unsigned)(3 - ex + 127) << 23;
  union { unsigned u; float f; } a;  a.u = au;
  int q = (int)rintf(a.f * iv.f);
  if (q >= 16) { q >>= 1; ex += 1; }
  unsigned bits;
  if (ex == -6 && q < 8) bits = (unsigned)q;
  else bits = (unsigned)(((ex + 7) << 3) | (q - 8));
  return (unsigned char)(s | bits);
}

#if defined(__has_builtin)
#if __has_builtin(__builtin_amdgcn_cvt_pk_fp8_f32)
#define PV_HW_FP8 1
#endif
#endif
__device__ __forceinline__ unsigned char pv_fp8_fast(float x){
#ifdef PV_HW_FP8
  return (unsigned char)__builtin_amdgcn_cvt_pk_fp8_f32(x, x, 0, false);
#else
  return pv_fp8(x);
#endif
}

// ---------------------------------------------------------------------------
// pv_prep_gru8: pack gru weights into fp8 MFMA B-fragment order, GATE-
// INTERLEAVED: tile T = jb*3 + ty (jb 0..16, ty in {r,z,n}) holds gate
// g = ty*261 + (jb*16 + l16).  (unchanged, verified r4/r5)
// ---------------------------------------------------------------------------
__global__ void pv_prep_gru8(const float* Whh, const float* Wih,
                             unsigned long long* wfp8){
  int idx = blockIdx.x*256 + threadIdx.x;   // < 51*9*64 = 29376
  if (idx >= 29376) return;
  int T = idx / 576;
  int rem = idx - T*576;
  int c = rem >> 6;
  int l = rem & 63;
  int l16 = l & 15;
  int quad = l >> 4;
  int jb = T / 3;
  int ty = T - jb*3;
  int j = jb*16 + l16;
  int g = ty*261 + j;
  unsigned long long v = 0ull;
  #pragma unroll
  for (int e = 0; e < 8; ++e) {
    int k = c*32 + quad*8 + e;
    float w = 0.0f;
    if (j < 261) {
      if (k < 261) w = Whh[g*261 + k];
      else if (k < 266 && ty < 2) w = Wih[g*261 + 256 + (k - 261)];
    }
    v |= (unsigned long long)pv_fp8(8.0f*w) << (8*e);
  }
  wfp8[idx] = v;
}

// ---------------------------------------------------------------------------
// pv_prep_wih: pack lstm_Wih (512x4096 f32) to bf16 row-major [512][4096].
// ---------------------------------------------------------------------------
__global__ __launch_bounds__(256) void pv_prep_wih(
    const float* __restrict__ Wih, unsigned* __restrict__ wihb)
{
  const int idx = blockIdx.x*256 + threadIdx.x;      // 262144 threads
  if (idx >= 262144) return;
  const float* src = Wih + idx*8;
  float4 a = *(const float4*)(src);
  float4 b = *(const float4*)(src + 4);
  uint4 o;
  o.x = pv_pack2(a.x, a.y);
  o.y = pv_pack2(a.z, a.w);
  o.z = pv_pack2(b.x, b.y);
  o.w = pv_pack2(b.z, b.w);
  *(uint4*)(wihb + idx*4) = o;
}

// ---------------------------------------------------------------------------
// pv_gemm3: r3 logic unchanged; r5 change = amdgpu_waves_per_eu(2,2) so the
// RA budgets 256 VGPRs (LDS 94 KB already limits to 1 block/CU = 2 waves/EU;
// the old 4-waves/EU RA target forced acc/frag spills).
// ---------------------------------------------------------------------------
__global__ __attribute__((amdgpu_waves_per_eu(2, 2)))
__launch_bounds__(512) void pv_gemm3(
    const float* __restrict__ pose, const float* __restrict__ projW,
    const float* __restrict__ projb, const unsigned* __restrict__ wihb,
    const float* __restrict__ bih, const float* __restrict__ bhh,
    float* __restrict__ xg)
{
  __shared__ __align__(16) unsigned As2[128*20];      // A bf16 [128][40s]
  __shared__ __align__(16) unsigned Bs2[2][512*20];   // B bf16 [512][40s], dbuf
  __shared__ __align__(16) float Ws2[2][320];         // W^T: [j*32+kl], bias 288+

  const int tid = threadIdx.x;
  const int m0 = blockIdx.x * 128;
  const int wave = tid >> 6, lane = tid & 63;
  const int wm = wave >> 2, wn = wave & 3;
  const int l16 = lane & 15, quad = lane >> 4;
  const int rl = tid >> 2, kq = tid & 3;       // A-gen: row rl, k-quarter kq

  float p[9];
  {
    const float* pr = pose + (m0 + rl)*9;
    #pragma unroll
    for (int j = 0; j < 9; ++j) p[j] = pr[j];
  }

  if (tid < 320) {
    Ws2[0][tid < 288 ? ((tid >> 5)*32 + (tid & 31)) : tid] =
        (tid < 288) ? projW[(tid & 31)*9 + (tid >> 5)] : projb[tid - 288];
  }
  #pragma unroll
  for (int i = 0; i < 4; ++i) {
    const int n = i*128 + rl;
    *(uint4*)(&Bs2[0][n*20 + kq*4]) = *(const uint4*)(wihb + n*2048 + kq*4);
  }
  __syncthreads();

  f32x4 acc[4][8];
  #pragma unroll
  for (int i = 0; i < 4; ++i)
    #pragma unroll
    for (int j = 0; j < 8; ++j) acc[i][j] = (f32x4){0.f,0.f,0.f,0.f};

  for (int kk = 0; kk < 128; ++kk) {
    const int cur = kk & 1, nxt = cur ^ 1;
    const int kn = kk + 1;

    uint4 bn0, bn1, bn2, bn3; float wv = 0.0f;
    if (kn < 128) {
      const unsigned* bsrc = wihb + kn*16 + kq*4;
      bn0 = *(const uint4*)(bsrc + (0*128 + rl)*2048);
      bn1 = *(const uint4*)(bsrc + (1*128 + rl)*2048);
      bn2 = *(const uint4*)(bsrc + (2*128 + rl)*2048);
      bn3 = *(const uint4*)(bsrc + (3*128 + rl)*2048);
      if (tid < 320)
        wv = (tid < 288) ? projW[kn*288 + (tid & 31)*9 + (tid >> 5)]
                         : projb[kn*32 + (tid - 288)];
    }

    {
      const float* W = Ws2[cur];
      f32x4 slo = *(const f32x4*)(W + 288 + kq*8);
      f32x4 shi = *(const f32x4*)(W + 292 + kq*8);
      #pragma unroll
      for (int j = 0; j < 9; ++j) {
        f32x4 wlo = *(const f32x4*)(W + j*32 + kq*8);
        f32x4 whi = *(const f32x4*)(W + j*32 + kq*8 + 4);
        slo += p[j]*wlo;
        shi += p[j]*whi;
      }
      #pragma unroll
      for (int e = 0; e < 4; ++e) {
        slo[e] = fmaxf(slo[e], 0.1f*slo[e]);
        shi[e] = fmaxf(shi[e], 0.1f*shi[e]);
      }
      uint4 av;
      av.x = pv_pack2(slo[0], slo[1]);
      av.y = pv_pack2(slo[2], slo[3]);
      av.z = pv_pack2(shi[0], shi[1]);
      av.w = pv_pack2(shi[2], shi[3]);
      *(uint4*)(&As2[rl*20 + kq*4]) = av;
    }

    if (kn < 128) {
      unsigned* bdst = &Bs2[nxt][rl*20 + kq*4];
      *(uint4*)(bdst + 0*128*20) = bn0;
      *(uint4*)(bdst + 1*128*20) = bn1;
      *(uint4*)(bdst + 2*128*20) = bn2;
      *(uint4*)(bdst + 3*128*20) = bn3;
      if (tid < 320)
        Ws2[nxt][tid < 288 ? ((tid >> 5)*32 + (tid & 31)) : tid] = wv;
    }
    __syncthreads();

    const unsigned short* As16 = (const unsigned short*)As2;
    const unsigned short* Bs16 = (const unsigned short*)Bs2[cur];
    s16x8 af[4];
    #pragma unroll
    for (int i = 0; i < 4; ++i)
      af[i] = *(const s16x8*)(As16 + (wm*64 + i*16 + l16)*40 + quad*8);
    #pragma unroll
    for (int j = 0; j < 8; ++j) {
      s16x8 bv = *(const s16x8*)(Bs16 + (wn*128 + j*16 + l16)*40 + quad*8);
      #pragma unroll
      for (int i = 0; i < 4; ++i)
        acc[i][j] = __builtin_amdgcn_mfma_f32_16x16x32_bf16(af[i], bv, acc[i][j], 0, 0, 0);
    }
    __syncthreads();
  }

  #pragma unroll
  for (int j = 0; j < 8; ++j) {
    int col = wn*128 + j*16 + l16;
    float bsum = bih[col] + bhh[col];
    #pragma unroll
    for (int i = 0; i < 4; ++i) {
      #pragma unroll
      for (int r = 0; r < 4; ++r) {
        int row = m0 + wm*64 + i*16 + quad*4 + r;
        int bb = row / 100;
        int tt = row - bb*100;
        xg[(tt*128 + bb)*512 + col] = acc[i][j][r] + bsum;
      }
    }
  }
}

// ---------------------------------------------------------------------------
// pv_gemm: old fused path (fallback when workspace is too small). Unchanged.
// ---------------------------------------------------------------------------
__global__ __launch_bounds__(256) void pv_gemm(
    const float* pose, const float* projW, const float* projb,
    const float* Wih, const float* bih, const float* bhh,
    float* xg)
{
  __shared__ __align__(16) unsigned As[128*24];
  __shared__ __align__(16) unsigned Bs[128*24];
  __shared__ float Ws[320];

  const int tid = threadIdx.x;
  const int m0 = blockIdx.x * 128;
  const int n0 = blockIdx.y * 128;

  const int rl = tid >> 1;
  const int kh = tid & 1;
  float p0,p1,p2,p3,p4,p5,p6,p7,p8;
  {
    const float* pr = pose + (m0 + rl) * 9;
    p0=pr[0]; p1=pr[1]; p2=pr[2]; p3=pr[3]; p4=pr[4];
    p5=pr[5]; p6=pr[6]; p7=pr[7]; p8=pr[8];
  }

  const int wave = tid >> 6;
  const int lane = tid & 63;
  const int wm = wave >> 1, wn = wave & 1;
  const int l16 = lane & 15, quad = lane >> 4;

  f32x4 acc[4][4];
  #pragma unroll
  for (int i = 0; i < 4; ++i)
    #pragma unroll
    for (int j = 0; j < 4; ++j) acc[i][j] = (f32x4){0.f,0.f,0.f,0.f};

  for (int kk = 0; kk < 128; ++kk) {
    __syncthreads();
    for (int idx = tid; idx < 320; idx += 256)
      Ws[idx] = (idx < 288) ? projW[kk*288 + idx] : projb[kk*32 + (idx - 288)];
    #pragma unroll
    for (int i = 0; i < 8; ++i) {
      int q = tid + i*256;
      int nl = q >> 4;
      int kp = q & 15;
      const float* src = Wih + (n0 + nl)*4096 + kk*32 + kp*2;
      Bs[nl*24 + kp] = pv_pack2(src[0], src[1]);
    }
    __syncthreads();
    {
      const int kbase = kh*16;
      const float* wbase = Ws + kbase*9;
      float av[16];
      #pragma unroll
      for (int u = 0; u < 16; ++u) {
        const float* wr = wbase + u*9;
        float s = Ws[288 + kbase + u]
                + p0*wr[0] + p1*wr[1] + p2*wr[2] + p3*wr[3] + p4*wr[4]
                + p5*wr[5] + p6*wr[6] + p7*wr[7] + p8*wr[8];
        av[u] = fmaxf(s, 0.1f*s);
      }
      #pragma unroll
      for (int q = 0; q < 8; ++q)
        As[rl*24 + kh*8 + q] = pv_pack2(av[2*q], av[2*q+1]);
    }
    __syncthreads();
    const unsigned short* As16 = (const unsigned short*)As;
    const unsigned short* Bs16 = (const unsigned short*)Bs;
    s16x8 af[4], bfv[4];
    #pragma unroll
    for (int i = 0; i < 4; ++i)
      af[i] = *(const s16x8*)(As16 + (wm*64 + i*16 + l16)*48 + quad*8);
    #pragma unroll
    for (int j = 0; j < 4; ++j)
      bfv[j] = *(const s16x8*)(Bs16 + (wn*64 + j*16 + l16)*48 + quad*8);
    #pragma unroll
    for (int i = 0; i < 4; ++i)
      #pragma unroll
      for (int j = 0; j < 4; ++j)
        acc[i][j] = __builtin_amdgcn_mfma_f32_16x16x32_bf16(af[i], bfv[j], acc[i][j], 0, 0, 0);
  }
  #pragma unroll
  for (int j = 0; j < 4; ++j) {
    int col = n0 + wn*64 + j*16 + l16;
    float bsum = bih[col] + bhh[col];
    #pragma unroll
    for (int i = 0; i < 4; ++i) {
      #pragma unroll
      for (int r = 0; r < 4; ++r) {
        int row = m0 + wm*64 + i*16 + quad*4 + r;
        int bb = row / 100;
        int tt = row - bb*100;
        xg[(tt*128 + bb)*512 + col] = acc[i][j][r] + bsum;
      }
    }
  }
}

// ---------------------------------------------------------------------------
// pv_lstm2: r4 logic unchanged; r5 change = amdgpu_waves_per_eu(2,2) so the
// ~140 live dwords (B frags 64 + xv/xn 32 + acc 16 + misc) stay resident.
// ---------------------------------------------------------------------------
__global__ __attribute__((amdgpu_waves_per_eu(2, 2)))
__launch_bounds__(512) void pv_lstm2(
    const float* __restrict__ xg, const float* __restrict__ Whh,
    float* __restrict__ hT)
{
  __shared__ __align__(16) unsigned short Hs2[2][16*136];
  const int tid = threadIdx.x;
  const int wv = tid >> 6;           // 0..7
  const int lane = tid & 63;
  const int l16 = lane & 15, quad = lane >> 4;
  const int m0 = blockIdx.x * 16;
  const int j = wv*16 + l16;         // hidden unit 0..127

  s16x8 bfr[4][4];
  #pragma unroll
  for (int ty = 0; ty < 4; ++ty) {
    const int g = ty*128 + j;
    #pragma unroll
    for (int c = 0; c < 4; ++c) {
      s16x8 v;
      #pragma unroll
      for (int e = 0; e < 8; ++e)
        v[e] = (short)pv_f2b(Whh[g*128 + c*32 + quad*8 + e]);
      bfr[ty][c] = v;
    }
  }
  for (int i = tid; i < 2*16*136; i += 512) ((unsigned short*)Hs2)[i] = 0;

  float cst[4] = {0.f, 0.f, 0.f, 0.f};
  const float* xbase = xg + (m0 + quad*4)*512 + j;

  float xv[4][4];
  #pragma unroll
  for (int r = 0; r < 4; ++r)
    #pragma unroll
    for (int ty = 0; ty < 4; ++ty)
      xv[r][ty] = xbase[(0*128 + r)*512 + ty*128];
  __syncthreads();

  for (int t = 0; t < 100; ++t) {
    const int cur = t & 1, nxt = cur ^ 1;
    float xn[4][4];
    if (t < 99) {
      #pragma unroll
      for (int r = 0; r < 4; ++r)
        #pragma unroll
        for (int ty = 0; ty < 4; ++ty)
          xn[r][ty] = xbase[((t+1)*128 + r)*512 + ty*128];
    }
    f32x4 acc[4];
    #pragma unroll
    for (int ty = 0; ty < 4; ++ty) acc[ty] = (f32x4){0.f,0.f,0.f,0.f};
    #pragma unroll
    for (int c = 0; c < 4; ++c) {
      s16x8 a = *(const s16x8*)(&Hs2[cur][l16*136 + c*32 + quad*8]);
      #pragma unroll
      for (int ty = 0; ty < 4; ++ty)
        acc[ty] = __builtin_amdgcn_mfma_f32_16x16x32_bf16(a, bfr[ty][c], acc[ty], 0, 0, 0);
    }
    #pragma unroll
    for (int r = 0; r < 4; ++r) {
      float gi = acc[0][r] + xv[r][0];
      float gf = acc[1][r] + xv[r][1];
      float gg = acc[2][r] + xv[r][2];
      float go = acc[3][r] + xv[r][3];
      float c_ = pv_sigm(gf)*cst[r] + pv_sigm(gi)*pv_tanh(gg);
      cst[r] = c_;
      float h = pv_sigm(go)*pv_tanh(c_);
      Hs2[nxt][(quad*4 + r)*136 + j] = pv_f2b(h);
      if (t == 99) hT[(m0 + quad*4 + r)*128 + j] = h;
    }
    if (t < 99) {
      #pragma unroll
      for (int r = 0; r < 4; ++r)
        #pragma unroll
        for (int ty = 0; ty < 4; ++ty)
          xv[r][ty] = xn[r][ty];
    }
    __syncthreads();
  }
}

// ---------------------------------------------------------------------------
// pv_head: unchanged.
// ---------------------------------------------------------------------------
__global__ __launch_bounds__(64) void pv_head(
    const float* hT, const float* eps,
    const float* muW, const float* mub,
    const float* lvW, const float* lvb,
    const float* fcW, const float* fcb,
    float* xvec, float* out)
{
  __shared__ float hrow[128];
  __shared__ float emb[64];
  const int b = blockIdx.x, j = threadIdx.x;
  hrow[j] = hT[b*128 + j];
  hrow[j + 64] = hT[b*128 + 64 + j];
  __syncthreads();
  float sm = mub[j], sl = lvb[j];
  for (int k = 0; k < 128; ++k) {
    sm += hrow[k]*muW[j*128 + k];
    sl += hrow[k]*lvW[j*128 + k];
  }
  float mu = fmaxf(sm, 0.1f*sm);
  float lv = fmaxf(sl, 0.1f*sl);
  lv = fminf(fmaxf(lv, -10.0f), 10.0f);
  float em = mu + eps[b*64 + j]*__expf(0.5f*lv);
  emb[j] = em;
  out[115200 + b*64 + j] = mu;
  out[123392 + b*64 + j] = lv;
  __syncthreads();
  for (int c4 = 0; c4 < 4; ++c4) {
    int c = c4*64 + j;
    float s = fcb[c];
    for (int k = 0; k < 64; ++k) s += emb[k]*fcW[c*64 + k];
    xvec[b*256 + c] = s;
  }
}

// ---------------------------------------------------------------------------
// pv_gxbase: unchanged.
// ---------------------------------------------------------------------------
__global__ __launch_bounds__(256) void pv_gxbase(
    const float* xvec, const float* Wih,
    const float* bih, const float* bhh, float* gxb)
{
  __shared__ float xs[8*256];
  const int tid = threadIdx.x;
  const int bg = blockIdx.x;
  const int gg = blockIdx.y;
  for (int i = tid; i < 2048; i += 256) xs[i] = xvec[bg*2048 + i];
  __syncthreads();
  const int g = gg*256 + tid;
  if (g >= 783) return;
  float bias = bih[g] + ((g < 522) ? bhh[g] : 0.0f);
  float a0=bias,a1=bias,a2=bias,a3=bias,a4=bias,a5=bias,a6=bias,a7=bias;
  const float* wr = Wih + g*261;
  for (int k = 0; k < 256; ++k) {
    float w = wr[k];
    a0 += xs[0*256 + k]*w; a1 += xs[1*256 + k]*w;
    a2 += xs[2*256 + k]*w; a3 += xs[3*256 + k]*w;
    a4 += xs[4*256 + k]*w; a5 += xs[5*256 + k]*w;
    a6 += xs[6*256 + k]*w; a7 += xs[7*256 + k]*w;
  }
  gxb[(bg*8 + 0)*783 + g] = a0; gxb[(bg*8 + 1)*783 + g] = a1;
  gxb[(bg*8 + 2)*783 + g] = a2; gxb[(bg*8 + 3)*783 + g] = a3;
  gxb[(bg*8 + 4)*783 + g] = a4; gxb[(bg*8 + 5)*783 + g] = a5;
  gxb[(bg*8 + 6)*783 + g] = a6; gxb[(bg*8 + 7)*783 + g] = a7;
}

// ---------------------------------------------------------------------------
// pv_gru3: r5 logic unchanged; r5b change = amdgpu_waves_per_eu(2,2) so the
// RA budgets 256 VGPRs and the 63-long B-fragment array stays RESIDENT
// (r5 counters: VGPR_Count=128 => per-step remat-reload of B from L2,
// the dominant cost in every GRU version so far).
// ---------------------------------------------------------------------------
__global__ __attribute__((amdgpu_waves_per_eu(2, 2)))
__launch_bounds__(512) void pv_gru3(
    const float* __restrict__ gxb, const unsigned long long* __restrict__ wfp8,
    const float* __restrict__ Wih, const float* __restrict__ bhh,
    const float* __restrict__ noise, float* __restrict__ hseq)
{
  __shared__ __align__(16) unsigned char A2[2][16*296];  // fp8 A, dbuf
  __shared__ __align__(16) float ns[1600];               // [t][m][i] raw noise
  __shared__ __align__(16) float DsT[3][4][16];          // tail acc exchange
  const int tid = threadIdx.x;
  const int wv = tid >> 6;           // 0..7
  const int lane = tid & 63;
  const int l16 = lane & 15, quad = lane >> 4;
  const int m0 = blockIdx.x * 4;
  const int hasTail = (wv < 3);

  // B fragments: slots 0..5 = group G (=s/3) x ty (=s%3); slot 6 = tail tile
  long bfr[7][9];
  #pragma unroll
  for (int s = 0; s < 6; ++s) {
    const int T = (wv*2 + s/3)*3 + (s % 3);
    #pragma unroll
    for (int c = 0; c < 9; ++c)
      bfr[s][c] = (long)wfp8[(T*9 + c)*64 + lane];
  }
  if (hasTail) {
    const int T = 48 + wv;           // tile ty = wv of jb-group 16
    #pragma unroll
    for (int c = 0; c < 9; ++c)
      bfr[6][c] = (long)wfp8[(T*9 + c)*64 + lane];
  } else {
    #pragma unroll
    for (int c = 0; c < 9; ++c) bfr[6][c] = 0;
  }

  // per-lane update state (quad-0): 2 unit-groups
  const int up = (quad == 0);
  float wn[2][5], bhhn[2], gxr[2][4], gxz[2][4], gxn[2][4], hu[2][4];
  #pragma unroll
  for (int G = 0; G < 2; ++G)
    #pragma unroll
    for (int r = 0; r < 4; ++r) hu[G][r] = 0.f;
  if (up) {
    #pragma unroll
    for (int G = 0; G < 2; ++G) {
      const int j = (wv*2 + G)*16 + l16;
      const float* wrow = Wih + (522 + j)*261 + 256;
      wn[G][0] = 0.1f*wrow[0]; wn[G][1] = 0.1f*wrow[1]; wn[G][2] = 0.1f*wrow[2];
      wn[G][3] = 0.1f*wrow[3]; wn[G][4] = wrow[4];
      bhhn[G] = bhh[522 + j];
      #pragma unroll
      for (int r = 0; r < 4; ++r) {
        const float* gb = gxb + (m0 + r)*783;
        gxr[G][r] = gb[j]; gxz[G][r] = gb[261 + j]; gxn[G][r] = gb[522 + j];
      }
    }
  }
  // wave-7 tail state (units 256..260)
  const int upT = (quad == 0) && (wv == 7) && (l16 < 5);
  float wnT[5], bhhnT = 0.f, gxrT[4], gxzT[4], gxnT[4], hTl[4];
  #pragma unroll
  for (int r = 0; r < 4; ++r) hTl[r] = 0.f;
  if (upT) {
    const int j = 256 + l16;
    const float* wrow = Wih + (522 + j)*261 + 256;
    wnT[0] = 0.1f*wrow[0]; wnT[1] = 0.1f*wrow[1]; wnT[2] = 0.1f*wrow[2];
    wnT[3] = 0.1f*wrow[3]; wnT[4] = wrow[4];
    bhhnT = bhh[522 + j];
    #pragma unroll
    for (int r = 0; r < 4; ++r) {
      const float* gb = gxb + (m0 + r)*783;
      gxrT[r] = gb[j]; gxzT[r] = gb[261 + j]; gxnT[r] = gb[522 + j];
    }
  }

  // prologue: zero A2 (both buffers), stage noise to LDS
  for (int i = tid; i < 2*16*296; i += 512) ((unsigned char*)A2)[i] = 0;
  for (int i = tid; i < 1600; i += 512) {
    const int t = i >> 4, m = (i >> 2) & 3, ii = i & 3;
    ns[i] = noise[(t*128 + m0 + m)*4 + ii];
  }
  __syncthreads();
  if (tid < 20) {   // t=0 noise/time cols (time_0 = 0)
    const int m = tid/5, i = tid - (tid/5)*5;
    float v = (i < 4) ? noise[(m0 + m)*4 + i]*0.1f : 0.0f;
    A2[0][m*296 + 261 + i] = pv_fp8(4.0f*v);
  }
  __syncthreads();

  const float inv32 = 1.0f/32.0f;
  for (int t = 0; t < 100; ++t) {
    const int cur = t & 1, nxt = cur ^ 1;
    f32x4 acc[7];
    #pragma unroll
    for (int s = 0; s < 7; ++s) acc[s] = (f32x4){0,0,0,0};
    #pragma unroll
    for (int c = 0; c < 9; ++c) {
      const long a = *(const long*)(&A2[cur][l16*296 + c*32 + quad*8]);
      #pragma unroll
      for (int s = 0; s < 7; ++s)
        if (s < 6 || hasTail)
          acc[s] = __builtin_amdgcn_mfma_f32_16x16x32_fp8_fp8(a, bfr[s][c], acc[s], 0, 0, 0);
    }
    if (hasTail && quad == 0) {
      #pragma unroll
      for (int r = 0; r < 4; ++r)
        DsT[wv][r][l16] = acc[6][r];
    }
    __syncthreads();   // barrier A: DsT visible

    if (up) {
      const float tv = (float)t * (1.0f/99.0f);
      float4 ne[4];
      #pragma unroll
      for (int r = 0; r < 4; ++r)
        ne[r] = *(const float4*)(&ns[t*16 + r*4]);
      #pragma unroll
      for (int G = 0; G < 2; ++G) {
        const int j = (wv*2 + G)*16 + l16;
        #pragma unroll
        for (int r = 0; r < 4; ++r) {
          float Dr = acc[G*3 + 0][r]*inv32 + gxr[G][r];
          float Dz = acc[G*3 + 1][r]*inv32 + gxz[G][r];
          float Dn = acc[G*3 + 2][r]*inv32;
          float nterm = ne[r].x*wn[G][0] + ne[r].y*wn[G][1] + ne[r].z*wn[G][2]
                      + ne[r].w*wn[G][3] + tv*wn[G][4];
          float r_ = pv_sigm(Dr);
          float z_ = pv_sigm(Dz);
          float n_ = pv_tanh(gxn[G][r] + nterm + r_*(Dn + bhhn[G]));
          hu[G][r] = (1.0f - z_)*n_ + z_*hu[G][r];
          hseq[(t*128 + m0 + r)*261 + j] = hu[G][r];
          A2[nxt][r*296 + j] = pv_fp8_fast(4.0f*hu[G][r]);
        }
      }
      if (upT) {
        const int j = 256 + l16;
        #pragma unroll
        for (int r = 0; r < 4; ++r) {
          float Dr = DsT[0][r][l16]*inv32 + gxrT[r];
          float Dz = DsT[1][r][l16]*inv32 + gxzT[r];
          float Dn = DsT[2][r][l16]*inv32;
          float nterm = ne[r].x*wnT[0] + ne[r].y*wnT[1] + ne[r].z*wnT[2]
                      + ne[r].w*wnT[3] + tv*wnT[4];
          float r_ = pv_sigm(Dr);
          float z_ = pv_sigm(Dz);
          float n_ = pv_tanh(gxnT[r] + nterm + r_*(Dn + bhhnT));
          hTl[r] = (1.0f - z_)*n_ + z_*hTl[r];
          hseq[(t*128 + m0 + r)*261 + j] = hTl[r];
          A2[nxt][r*296 + j] = pv_fp8_fast(4.0f*hTl[r]);
        }
      }
    }
    // noise/time cols for t+1 (idle quad2/3 lanes of wave 1)
    if (t < 99 && wv == 1 && lane >= 32 && lane < 52) {
      const int k = lane - 32;
      const int m = k/5, i = k - (k/5)*5;
      float v = (i < 4) ? ns[(t+1)*16 + m*4 + i]*0.1f
                        : (t+1)*(1.0f/99.0f);
      A2[nxt][m*296 + 261 + i] = pv_fp8(4.0f*v);
    }
    __syncthreads();   // barrier B: A2[nxt] complete
  }
}

// ---------------------------------------------------------------------------
// pv_frames: unchanged.
// ---------------------------------------------------------------------------
__global__ __launch_bounds__(256) void pv_frames(
    const float* hseq, const float* W1, const float* b1,
    const float* W2, const float* b2, float* out)
{
  __shared__ __align__(16) float h16[16*264];
  __shared__ unsigned w1p[64*133];
  __shared__ float f1s[16*66];
  __shared__ float w2s[576];
  const int tid = threadIdx.x;
  const int r0 = blockIdx.x * 16;    // rows rt = t*128 + b
  for (int i = tid; i < 16*264; i += 256) {
    int r = i / 264, k = i - r*264;
    h16[i] = (k < 261) ? hseq[(r0 + r)*261 + k] : 0.0f;
  }
  for (int i = tid; i < 64*131; i += 256) {
    int c = i/131, kp = i - (i/131)*131;
    int k = kp*2;
    float a0 = W1[c*261 + k];
    float a1 = (k + 1 < 261) ? W1[c*261 + k + 1] : 0.0f;
    w1p[c*133 + kp] = pv_pack2(a0, a1);
  }
  for (int i = tid; i < 576; i += 256) w2s[i] = W2[i];
  __syncthreads();
  #pragma unroll
  for (int e = 0; e < 4; ++e) {
    const int el = tid + e*256;
    const int r = el >> 6, c = el & 63;
    float s = b1[c];
    const unsigned* wp = w1p + c*133;
    const float* hr = h16 + r*264;
    for (int kp = 0; kp < 131; ++kp) {
      unsigned w = wp[kp];
      s += pv_lo(w)*hr[2*kp] + pv_hi(w)*hr[2*kp + 1];
    }
    f1s[r*66 + c] = fmaxf(s, 0.2f*s);
  }
  __syncthreads();
  if (tid < 144) {
    const int r = tid/9, oc = tid - (tid/9)*9;
    float s = b2[oc];
    const float* fr = f1s + r*66;
    const float* w = w2s + oc*64;
    #pragma unroll 8
    for (int k = 0; k < 64; ++k) s += fr[k]*w[k];
    const int rt = r0 + r;
    const int tt = rt >> 7, bb = rt & 127;
    out[bb*900 + tt*9 + oc] = pv_sigm(s);
  }
}

// ---------------------------------------------------------------------------
extern "C" __attribute__((visibility("default")))
void kernel_launch(void* const* d_in, const int* in_sizes, int n_in,
                   void* d_out, int out_size, void* d_ws, size_t ws_size,
                   hipStream_t stream)
{
  (void)in_sizes; (void)n_in; (void)out_size;
  const float* input_data = (const float*)d_in[0];
  const float* eps        = (const float*)d_in[1];
  const float* noise_eps  = (const float*)d_in[2];
  const float* proj_W     = (const float*)d_in[3];
  const float* proj_b     = (const float*)d_in[4];
  const float* lstm_Wih   = (const float*)d_in[5];
  const float* lstm_Whh   = (const float*)d_in[6];
  const float* lstm_bih   = (const float*)d_in[7];
  const float* lstm_bhh   = (const float*)d_in[8];
  const float* mu_W       = (const float*)d_in[9];
  const float* mu_b       = (const float*)d_in[10];
  const float* lv_W       = (const float*)d_in[11];
  const float* lv_b       = (const float*)d_in[12];
  const float* fcin_W     = (const float*)d_in[13];
  const float* fcin_b     = (const float*)d_in[14];
  const float* gru_Wih    = (const float*)d_in[15];
  const float* gru_Whh    = (const float*)d_in[16];
  const float* gru_bih    = (const float*)d_in[17];
  const float* gru_bhh    = (const float*)d_in[18];
  const float* jf_W1      = (const float*)d_in[19];
  const float* jf_b1      = (const float*)d_in[20];
  const float* jf_W2      = (const float*)d_in[21];
  const float* jf_b2      = (const float*)d_in[22];

  char* w = (char*)d_ws;
  float*              xg   = (float*)(w);                          // 26,214,400 B
  unsigned long long* wfp8 = (unsigned long long*)(w + 26214400);  //    235,008 B
  float*              hT   = (float*)(w + 26449408);               //     65,536 B
  float*              xvec = (float*)(w + 26514944);               //    131,072 B
  float*              gxb  = (float*)(w + 26646016);               //    400,896 B
  float*              hseq = (float*)(w + 27046912);               // 13,363,200 B (end 40,410,112)
  unsigned*           wihb = (unsigned*)(w + 40410112);            //  4,194,304 B (end 44,604,416)
  float*              outf = (float*)d_out;

  const int use_split = (ws_size >= (size_t)44604416ull);

  pv_prep_gru8<<<115, 256, 0, stream>>>(gru_Whh, gru_Wih, wfp8);
  if (use_split) {
    pv_prep_wih<<<1024, 256, 0, stream>>>(lstm_Wih, wihb);
    pv_gemm3<<<100, 512, 0, stream>>>(input_data, proj_W, proj_b, wihb,
                                      lstm_bih, lstm_bhh, xg);
  } else {
    pv_gemm<<<dim3(100, 4), 256, 0, stream>>>(input_data, proj_W, proj_b,
                                              lstm_Wih, lstm_bih, lstm_bhh, xg);
  }
  pv_lstm2<<<8, 512, 0, stream>>>(xg, lstm_Whh, hT);
  pv_head<<<128, 64, 0, stream>>>(hT, eps, mu_W, mu_b, lv_W, lv_b,
                                  fcin_W, fcin_b, xvec, outf);
  pv_gxbase<<<dim3(16, 4), 256, 0, stream>>>(xvec, gru_Wih, gru_bih, gru_bhh, gxb);
  pv_gru3<<<32, 512, 0, stream>>>(gxb, wfp8, gru_Wih, gru_bhh, noise_eps, hseq);
  pv_frames<<<800, 256, 0, stream>>>(hseq, jf_W1, jf_b1, jf_W2, jf_b2, outf);
}

// Round 7
// 955.589 us; speedup vs baseline: 1.0328x; 1.0328x over previous
//
#include <hip/hip_runtime.h>
#include <hip/hip_bf16.h>

typedef float f32x4 __attribute__((ext_vector_type(4)));
typedef short s16x8 __attribute__((ext_vector_type(8)));

__device__ __forceinline__ float pv_sigm(float x){ return 1.0f/(1.0f + __expf(-x)); }
__device__ __forceinline__ float pv_tanh(float x){ float e = __expf(2.0f*x); return 1.0f - 2.0f/(e + 1.0f); }

__device__ __forceinline__ unsigned short pv_f2b(float x){
  union { float f; unsigned u; } c; c.f = x;
  unsigned r = (c.u + 0x7fffu + ((c.u >> 16) & 1u)) >> 16;
  return (unsigned short)r;
}
__device__ __forceinline__ unsigned pv_pack2(float a, float b){
  return ((unsigned)pv_f2b(b) << 16) | (unsigned)pv_f2b(a);
}
__device__ __forceinline__ float pv_lo(unsigned u){
  union { unsigned u; float f; } c; c.u = u << 16; return c.f;
}
__device__ __forceinline__ float pv_hi(unsigned u){
  union { unsigned u; float f; } c; c.u = u & 0xffff0000u; return c.f;
}

// manual OCP e4m3fn encode (RNE); valid for |x| < 448
__device__ __forceinline__ unsigned char pv_fp8(float x){
  union { float f; unsigned u; } c; c.f = x;
  unsigned s = (c.u >> 24) & 0x80u;
  unsigned au = c.u & 0x7fffffffu;
  if (au == 0u) return (unsigned char)s;
  int ex = (int)(au >> 23) - 127;
  if (ex < -6) ex = -6;
  union { unsigned u; float f; } iv; iv.u = (unsigned)(3 - ex + 127) << 23;
  union { unsigned u; float f; } a;  a.u = au;
  int q = (int)rintf(a.f * iv.f);
  if (q >= 16) { q >>= 1; ex += 1; }
  unsigned bits;
  if (ex == -6 && q < 8) bits = (unsigned)q;
  else bits = (unsigned)(((ex + 7) << 3) | (q - 8));
  return (unsigned char)(s | bits);
}

#if defined(__has_builtin)
#if __has_builtin(__builtin_amdgcn_cvt_pk_fp8_f32)
#define PV_HW_FP8 1
#endif
#endif
__device__ __forceinline__ unsigned char pv_fp8_fast(float x){
#ifdef PV_HW_FP8
  return (unsigned char)__builtin_amdgcn_cvt_pk_fp8_f32(x, x, 0, false);
#else
  return pv_fp8(x);
#endif
}

// ---------------------------------------------------------------------------
// pv_prep_gru8: pack gru weights into fp8 MFMA B-fragment order, GATE-
// INTERLEAVED: tile T = jb*3 + ty (jb 0..16, ty in {r,z,n}) holds gate
// g = ty*261 + (jb*16 + l16).  (unchanged, verified r4/r5/r6)
// ---------------------------------------------------------------------------
__global__ void pv_prep_gru8(const float* Whh, const float* Wih,
                             unsigned long long* wfp8){
  int idx = blockIdx.x*256 + threadIdx.x;   // < 51*9*64 = 29376
  if (idx >= 29376) return;
  int T = idx / 576;
  int rem = idx - T*576;
  int c = rem >> 6;
  int l = rem & 63;
  int l16 = l & 15;
  int quad = l >> 4;
  int jb = T / 3;
  int ty = T - jb*3;
  int j = jb*16 + l16;
  int g = ty*261 + j;
  unsigned long long v = 0ull;
  #pragma unroll
  for (int e = 0; e < 8; ++e) {
    int k = c*32 + quad*8 + e;
    float w = 0.0f;
    if (j < 261) {
      if (k < 261) w = Whh[g*261 + k];
      else if (k < 266 && ty < 2) w = Wih[g*261 + 256 + (k - 261)];
    }
    v |= (unsigned long long)pv_fp8(8.0f*w) << (8*e);
  }
  wfp8[idx] = v;
}

// ---------------------------------------------------------------------------
// pv_prep_wih: pack lstm_Wih (512x4096 f32) to bf16 row-major [512][4096].
// ---------------------------------------------------------------------------
__global__ __launch_bounds__(256) void pv_prep_wih(
    const float* __restrict__ Wih, unsigned* __restrict__ wihb)
{
  const int idx = blockIdx.x*256 + threadIdx.x;      // 262144 threads
  if (idx >= 262144) return;
  const float* src = Wih + idx*8;
  float4 a = *(const float4*)(src);
  float4 b = *(const float4*)(src + 4);
  uint4 o;
  o.x = pv_pack2(a.x, a.y);
  o.y = pv_pack2(a.z, a.w);
  o.z = pv_pack2(b.x, b.y);
  o.w = pv_pack2(b.z, b.w);
  *(uint4*)(wihb + idx*4) = o;
}

// ---------------------------------------------------------------------------
// pv_gemm3: unchanged from round 6 (passed).
// ---------------------------------------------------------------------------
__global__ __attribute__((amdgpu_waves_per_eu(2, 2)))
__launch_bounds__(512) void pv_gemm3(
    const float* __restrict__ pose, const float* __restrict__ projW,
    const float* __restrict__ projb, const unsigned* __restrict__ wihb,
    const float* __restrict__ bih, const float* __restrict__ bhh,
    float* __restrict__ xg)
{
  __shared__ __align__(16) unsigned As2[128*20];      // A bf16 [128][40s]
  __shared__ __align__(16) unsigned Bs2[2][512*20];   // B bf16 [512][40s], dbuf
  __shared__ __align__(16) float Ws2[2][320];         // W^T: [j*32+kl], bias 288+

  const int tid = threadIdx.x;
  const int m0 = blockIdx.x * 128;
  const int wave = tid >> 6, lane = tid & 63;
  const int wm = wave >> 2, wn = wave & 3;
  const int l16 = lane & 15, quad = lane >> 4;
  const int rl = tid >> 2, kq = tid & 3;       // A-gen: row rl, k-quarter kq

  float p[9];
  {
    const float* pr = pose + (m0 + rl)*9;
    #pragma unroll
    for (int j = 0; j < 9; ++j) p[j] = pr[j];
  }

  if (tid < 320) {
    Ws2[0][tid < 288 ? ((tid >> 5)*32 + (tid & 31)) : tid] =
        (tid < 288) ? projW[(tid & 31)*9 + (tid >> 5)] : projb[tid - 288];
  }
  #pragma unroll
  for (int i = 0; i < 4; ++i) {
    const int n = i*128 + rl;
    *(uint4*)(&Bs2[0][n*20 + kq*4]) = *(const uint4*)(wihb + n*2048 + kq*4);
  }
  __syncthreads();

  f32x4 acc[4][8];
  #pragma unroll
  for (int i = 0; i < 4; ++i)
    #pragma unroll
    for (int j = 0; j < 8; ++j) acc[i][j] = (f32x4){0.f,0.f,0.f,0.f};

  for (int kk = 0; kk < 128; ++kk) {
    const int cur = kk & 1, nxt = cur ^ 1;
    const int kn = kk + 1;

    uint4 bn0, bn1, bn2, bn3; float wv = 0.0f;
    if (kn < 128) {
      const unsigned* bsrc = wihb + kn*16 + kq*4;
      bn0 = *(const uint4*)(bsrc + (0*128 + rl)*2048);
      bn1 = *(const uint4*)(bsrc + (1*128 + rl)*2048);
      bn2 = *(const uint4*)(bsrc + (2*128 + rl)*2048);
      bn3 = *(const uint4*)(bsrc + (3*128 + rl)*2048);
      if (tid < 320)
        wv = (tid < 288) ? projW[kn*288 + (tid & 31)*9 + (tid >> 5)]
                         : projb[kn*32 + (tid - 288)];
    }

    {
      const float* W = Ws2[cur];
      f32x4 slo = *(const f32x4*)(W + 288 + kq*8);
      f32x4 shi = *(const f32x4*)(W + 292 + kq*8);
      #pragma unroll
      for (int j = 0; j < 9; ++j) {
        f32x4 wlo = *(const f32x4*)(W + j*32 + kq*8);
        f32x4 whi = *(const f32x4*)(W + j*32 + kq*8 + 4);
        slo += p[j]*wlo;
        shi += p[j]*whi;
      }
      #pragma unroll
      for (int e = 0; e < 4; ++e) {
        slo[e] = fmaxf(slo[e], 0.1f*slo[e]);
        shi[e] = fmaxf(shi[e], 0.1f*shi[e]);
      }
      uint4 av;
      av.x = pv_pack2(slo[0], slo[1]);
      av.y = pv_pack2(slo[2], slo[3]);
      av.z = pv_pack2(shi[0], shi[1]);
      av.w = pv_pack2(shi[2], shi[3]);
      *(uint4*)(&As2[rl*20 + kq*4]) = av;
    }

    if (kn < 128) {
      unsigned* bdst = &Bs2[nxt][rl*20 + kq*4];
      *(uint4*)(bdst + 0*128*20) = bn0;
      *(uint4*)(bdst + 1*128*20) = bn1;
      *(uint4*)(bdst + 2*128*20) = bn2;
      *(uint4*)(bdst + 3*128*20) = bn3;
      if (tid < 320)
        Ws2[nxt][tid < 288 ? ((tid >> 5)*32 + (tid & 31)) : tid] = wv;
    }
    __syncthreads();

    const unsigned short* As16 = (const unsigned short*)As2;
    const unsigned short* Bs16 = (const unsigned short*)Bs2[cur];
    s16x8 af[4];
    #pragma unroll
    for (int i = 0; i < 4; ++i)
      af[i] = *(const s16x8*)(As16 + (wm*64 + i*16 + l16)*40 + quad*8);
    #pragma unroll
    for (int j = 0; j < 8; ++j) {
      s16x8 bv = *(const s16x8*)(Bs16 + (wn*128 + j*16 + l16)*40 + quad*8);
      #pragma unroll
      for (int i = 0; i < 4; ++i)
        acc[i][j] = __builtin_amdgcn_mfma_f32_16x16x32_bf16(af[i], bv, acc[i][j], 0, 0, 0);
    }
    __syncthreads();
  }

  #pragma unroll
  for (int j = 0; j < 8; ++j) {
    int col = wn*128 + j*16 + l16;
    float bsum = bih[col] + bhh[col];
    #pragma unroll
    for (int i = 0; i < 4; ++i) {
      #pragma unroll
      for (int r = 0; r < 4; ++r) {
        int row = m0 + wm*64 + i*16 + quad*4 + r;
        int bb = row / 100;
        int tt = row - bb*100;
        xg[(tt*128 + bb)*512 + col] = acc[i][j][r] + bsum;
      }
    }
  }
}

// ---------------------------------------------------------------------------
// pv_gemm: old fused path (fallback when workspace is too small). Unchanged.
// ---------------------------------------------------------------------------
__global__ __launch_bounds__(256) void pv_gemm(
    const float* pose, const float* projW, const float* projb,
    const float* Wih, const float* bih, const float* bhh,
    float* xg)
{
  __shared__ __align__(16) unsigned As[128*24];
  __shared__ __align__(16) unsigned Bs[128*24];
  __shared__ float Ws[320];

  const int tid = threadIdx.x;
  const int m0 = blockIdx.x * 128;
  const int n0 = blockIdx.y * 128;

  const int rl = tid >> 1;
  const int kh = tid & 1;
  float p0,p1,p2,p3,p4,p5,p6,p7,p8;
  {
    const float* pr = pose + (m0 + rl) * 9;
    p0=pr[0]; p1=pr[1]; p2=pr[2]; p3=pr[3]; p4=pr[4];
    p5=pr[5]; p6=pr[6]; p7=pr[7]; p8=pr[8];
  }

  const int wave = tid >> 6;
  const int lane = tid & 63;
  const int wm = wave >> 1, wn = wave & 1;
  const int l16 = lane & 15, quad = lane >> 4;

  f32x4 acc[4][4];
  #pragma unroll
  for (int i = 0; i < 4; ++i)
    #pragma unroll
    for (int j = 0; j < 4; ++j) acc[i][j] = (f32x4){0.f,0.f,0.f,0.f};

  for (int kk = 0; kk < 128; ++kk) {
    __syncthreads();
    for (int idx = tid; idx < 320; idx += 256)
      Ws[idx] = (idx < 288) ? projW[kk*288 + idx] : projb[kk*32 + (idx - 288)];
    #pragma unroll
    for (int i = 0; i < 8; ++i) {
      int q = tid + i*256;
      int nl = q >> 4;
      int kp = q & 15;
      const float* src = Wih + (n0 + nl)*4096 + kk*32 + kp*2;
      Bs[nl*24 + kp] = pv_pack2(src[0], src[1]);
    }
    __syncthreads();
    {
      const int kbase = kh*16;
      const float* wbase = Ws + kbase*9;
      float av[16];
      #pragma unroll
      for (int u = 0; u < 16; ++u) {
        const float* wr = wbase + u*9;
        float s = Ws[288 + kbase + u]
                + p0*wr[0] + p1*wr[1] + p2*wr[2] + p3*wr[3] + p4*wr[4]
                + p5*wr[5] + p6*wr[6] + p7*wr[7] + p8*wr[8];
        av[u] = fmaxf(s, 0.1f*s);
      }
      #pragma unroll
      for (int q = 0; q < 8; ++q)
        As[rl*24 + kh*8 + q] = pv_pack2(av[2*q], av[2*q+1]);
    }
    __syncthreads();
    const unsigned short* As16 = (const unsigned short*)As;
    const unsigned short* Bs16 = (const unsigned short*)Bs;
    s16x8 af[4], bfv[4];
    #pragma unroll
    for (int i = 0; i < 4; ++i)
      af[i] = *(const s16x8*)(As16 + (wm*64 + i*16 + l16)*48 + quad*8);
    #pragma unroll
    for (int j = 0; j < 4; ++j)
      bfv[j] = *(const s16x8*)(Bs16 + (wn*64 + j*16 + l16)*48 + quad*8);
    #pragma unroll
    for (int i = 0; i < 4; ++i)
      #pragma unroll
      for (int j = 0; j < 4; ++j)
        acc[i][j] = __builtin_amdgcn_mfma_f32_16x16x32_bf16(af[i], bfv[j], acc[i][j], 0, 0, 0);
  }
  #pragma unroll
  for (int j = 0; j < 4; ++j) {
    int col = n0 + wn*64 + j*16 + l16;
    float bsum = bih[col] + bhh[col];
    #pragma unroll
    for (int i = 0; i < 4; ++i) {
      #pragma unroll
      for (int r = 0; r < 4; ++r) {
        int row = m0 + wm*64 + i*16 + quad*4 + r;
        int bb = row / 100;
        int tt = row - bb*100;
        xg[(tt*128 + bb)*512 + col] = acc[i][j][r] + bsum;
      }
    }
  }
}

// ---------------------------------------------------------------------------
// pv_lstm2: unchanged from round 6 (passed).
// ---------------------------------------------------------------------------
__global__ __attribute__((amdgpu_waves_per_eu(2, 2)))
__launch_bounds__(512) void pv_lstm2(
    const float* __restrict__ xg, const float* __restrict__ Whh,
    float* __restrict__ hT)
{
  __shared__ __align__(16) unsigned short Hs2[2][16*136];
  const int tid = threadIdx.x;
  const int wv = tid >> 6;           // 0..7
  const int lane = tid & 63;
  const int l16 = lane & 15, quad = lane >> 4;
  const int m0 = blockIdx.x * 16;
  const int j = wv*16 + l16;         // hidden unit 0..127

  s16x8 bfr[4][4];
  #pragma unroll
  for (int ty = 0; ty < 4; ++ty) {
    const int g = ty*128 + j;
    #pragma unroll
    for (int c = 0; c < 4; ++c) {
      s16x8 v;
      #pragma unroll
      for (int e = 0; e < 8; ++e)
        v[e] = (short)pv_f2b(Whh[g*128 + c*32 + quad*8 + e]);
      bfr[ty][c] = v;
    }
  }
  for (int i = tid; i < 2*16*136; i += 512) ((unsigned short*)Hs2)[i] = 0;

  float cst[4] = {0.f, 0.f, 0.f, 0.f};
  const float* xbase = xg + (m0 + quad*4)*512 + j;

  float xv[4][4];
  #pragma unroll
  for (int r = 0; r < 4; ++r)
    #pragma unroll
    for (int ty = 0; ty < 4; ++ty)
      xv[r][ty] = xbase[(0*128 + r)*512 + ty*128];
  __syncthreads();

  for (int t = 0; t < 100; ++t) {
    const int cur = t & 1, nxt = cur ^ 1;
    float xn[4][4];
    if (t < 99) {
      #pragma unroll
      for (int r = 0; r < 4; ++r)
        #pragma unroll
        for (int ty = 0; ty < 4; ++ty)
          xn[r][ty] = xbase[((t+1)*128 + r)*512 + ty*128];
    }
    f32x4 acc[4];
    #pragma unroll
    for (int ty = 0; ty < 4; ++ty) acc[ty] = (f32x4){0.f,0.f,0.f,0.f};
    #pragma unroll
    for (int c = 0; c < 4; ++c) {
      s16x8 a = *(const s16x8*)(&Hs2[cur][l16*136 + c*32 + quad*8]);
      #pragma unroll
      for (int ty = 0; ty < 4; ++ty)
        acc[ty] = __builtin_amdgcn_mfma_f32_16x16x32_bf16(a, bfr[ty][c], acc[ty], 0, 0, 0);
    }
    #pragma unroll
    for (int r = 0; r < 4; ++r) {
      float gi = acc[0][r] + xv[r][0];
      float gf = acc[1][r] + xv[r][1];
      float gg = acc[2][r] + xv[r][2];
      float go = acc[3][r] + xv[r][3];
      float c_ = pv_sigm(gf)*cst[r] + pv_sigm(gi)*pv_tanh(gg);
      cst[r] = c_;
      float h = pv_sigm(go)*pv_tanh(c_);
      Hs2[nxt][(quad*4 + r)*136 + j] = pv_f2b(h);
      if (t == 99) hT[(m0 + quad*4 + r)*128 + j] = h;
    }
    if (t < 99) {
      #pragma unroll
      for (int r = 0; r < 4; ++r)
        #pragma unroll
        for (int ty = 0; ty < 4; ++ty)
          xv[r][ty] = xn[r][ty];
    }
    __syncthreads();
  }
}

// ---------------------------------------------------------------------------
// pv_head: unchanged.
// ---------------------------------------------------------------------------
__global__ __launch_bounds__(64) void pv_head(
    const float* hT, const float* eps,
    const float* muW, const float* mub,
    const float* lvW, const float* lvb,
    const float* fcW, const float* fcb,
    float* xvec, float* out)
{
  __shared__ float hrow[128];
  __shared__ float emb[64];
  const int b = blockIdx.x, j = threadIdx.x;
  hrow[j] = hT[b*128 + j];
  hrow[j + 64] = hT[b*128 + 64 + j];
  __syncthreads();
  float sm = mub[j], sl = lvb[j];
  for (int k = 0; k < 128; ++k) {
    sm += hrow[k]*muW[j*128 + k];
    sl += hrow[k]*lvW[j*128 + k];
  }
  float mu = fmaxf(sm, 0.1f*sm);
  float lv = fmaxf(sl, 0.1f*sl);
  lv = fminf(fmaxf(lv, -10.0f), 10.0f);
  float em = mu + eps[b*64 + j]*__expf(0.5f*lv);
  emb[j] = em;
  out[115200 + b*64 + j] = mu;
  out[123392 + b*64 + j] = lv;
  __syncthreads();
  for (int c4 = 0; c4 < 4; ++c4) {
    int c = c4*64 + j;
    float s = fcb[c];
    for (int k = 0; k < 64; ++k) s += emb[k]*fcW[c*64 + k];
    xvec[b*256 + c] = s;
  }
}

// ---------------------------------------------------------------------------
// pv_gxbase: unchanged.
// ---------------------------------------------------------------------------
__global__ __launch_bounds__(256) void pv_gxbase(
    const float* xvec, const float* Wih,
    const float* bih, const float* bhh, float* gxb)
{
  __shared__ float xs[8*256];
  const int tid = threadIdx.x;
  const int bg = blockIdx.x;
  const int gg = blockIdx.y;
  for (int i = tid; i < 2048; i += 256) xs[i] = xvec[bg*2048 + i];
  __syncthreads();
  const int g = gg*256 + tid;
  if (g >= 783) return;
  float bias = bih[g] + ((g < 522) ? bhh[g] : 0.0f);
  float a0=bias,a1=bias,a2=bias,a3=bias,a4=bias,a5=bias,a6=bias,a7=bias;
  const float* wr = Wih + g*261;
  for (int k = 0; k < 256; ++k) {
    float w = wr[k];
    a0 += xs[0*256 + k]*w; a1 += xs[1*256 + k]*w;
    a2 += xs[2*256 + k]*w; a3 += xs[3*256 + k]*w;
    a4 += xs[4*256 + k]*w; a5 += xs[5*256 + k]*w;
    a6 += xs[6*256 + k]*w; a7 += xs[7*256 + k]*w;
  }
  gxb[(bg*8 + 0)*783 + g] = a0; gxb[(bg*8 + 1)*783 + g] = a1;
  gxb[(bg*8 + 2)*783 + g] = a2; gxb[(bg*8 + 3)*783 + g] = a3;
  gxb[(bg*8 + 4)*783 + g] = a4; gxb[(bg*8 + 5)*783 + g] = a5;
  gxb[(bg*8 + 6)*783 + g] = a6; gxb[(bg*8 + 7)*783 + g] = a7;
}

// ---------------------------------------------------------------------------
// pv_gru3: r6 logic unchanged; r7 change = ANTI-REMAT PINNING.  r5/r6
// counters proved the RA satisfies its 128-VGPR occupancy target by
// REMATERIALIZING the loop-invariant B-fragment global loads every step
// (VGPR_Count=128 both rounds, ~10kcyc/step).  asm volatile "+v" pins make
// each fragment an opaque def the RA cannot recompute => it must keep them
// live (budget 256 via __launch_bounds__(512,2); RA degrades occupancy
// before spilling).  Same pin on the loop-invariant update-state scalars.
// Math unchanged; inactive-lane state zero-initialized before pinning.
// ---------------------------------------------------------------------------
__global__ __launch_bounds__(512, 2) void pv_gru3(
    const float* __restrict__ gxb, const unsigned long long* __restrict__ wfp8,
    const float* __restrict__ Wih, const float* __restrict__ bhh,
    const float* __restrict__ noise, float* __restrict__ hseq)
{
  __shared__ __align__(16) unsigned char A2[2][16*296];  // fp8 A, dbuf
  __shared__ __align__(16) float ns[1600];               // [t][m][i] raw noise
  __shared__ __align__(16) float DsT[3][4][16];          // tail acc exchange
  const int tid = threadIdx.x;
  const int wv = tid >> 6;           // 0..7
  const int lane = tid & 63;
  const int l16 = lane & 15, quad = lane >> 4;
  const int m0 = blockIdx.x * 4;
  const int hasTail = (wv < 3);

  // B fragments: slots 0..5 = group G (=s/3) x ty (=s%3); slot 6 = tail tile
  long bfr[7][9];
  #pragma unroll
  for (int s = 0; s < 6; ++s) {
    const int T = (wv*2 + s/3)*3 + (s % 3);
    #pragma unroll
    for (int c = 0; c < 9; ++c)
      bfr[s][c] = (long)wfp8[(T*9 + c)*64 + lane];
  }
  if (hasTail) {
    const int T = 48 + wv;           // tile ty = wv of jb-group 16
    #pragma unroll
    for (int c = 0; c < 9; ++c)
      bfr[6][c] = (long)wfp8[(T*9 + c)*64 + lane];
  } else {
    #pragma unroll
    for (int c = 0; c < 9; ++c) bfr[6][c] = 0;
  }
  // ---- anti-remat pin: opaque def, RA cannot reload these each step ----
  #pragma unroll
  for (int s = 0; s < 7; ++s)
    #pragma unroll
    for (int c = 0; c < 9; ++c)
      asm volatile("" : "+v"(bfr[s][c]));

  // per-lane update state (quad-0): 2 unit-groups (zero-init all lanes)
  const int up = (quad == 0);
  float wn[2][5], bhhn[2], gxr[2][4], gxz[2][4], gxn[2][4], hu[2][4];
  #pragma unroll
  for (int G = 0; G < 2; ++G) {
    #pragma unroll
    for (int k = 0; k < 5; ++k) wn[G][k] = 0.f;
    bhhn[G] = 0.f;
    #pragma unroll
    for (int r = 0; r < 4; ++r) {
      gxr[G][r] = 0.f; gxz[G][r] = 0.f; gxn[G][r] = 0.f; hu[G][r] = 0.f;
    }
  }
  if (up) {
    #pragma unroll
    for (int G = 0; G < 2; ++G) {
      const int j = (wv*2 + G)*16 + l16;
      const float* wrow = Wih + (522 + j)*261 + 256;
      wn[G][0] = 0.1f*wrow[0]; wn[G][1] = 0.1f*wrow[1]; wn[G][2] = 0.1f*wrow[2];
      wn[G][3] = 0.1f*wrow[3]; wn[G][4] = wrow[4];
      bhhn[G] = bhh[522 + j];
      #pragma unroll
      for (int r = 0; r < 4; ++r) {
        const float* gb = gxb + (m0 + r)*783;
        gxr[G][r] = gb[j]; gxz[G][r] = gb[261 + j]; gxn[G][r] = gb[522 + j];
      }
    }
  }
  // wave-7 tail state (units 256..260), zero-init all lanes
  const int upT = (quad == 0) && (wv == 7) && (l16 < 5);
  float wnT[5], bhhnT = 0.f, gxrT[4], gxzT[4], gxnT[4], hTl[4];
  #pragma unroll
  for (int k = 0; k < 5; ++k) wnT[k] = 0.f;
  #pragma unroll
  for (int r = 0; r < 4; ++r) { gxrT[r] = 0.f; gxzT[r] = 0.f; gxnT[r] = 0.f; hTl[r] = 0.f; }
  if (upT) {
    const int j = 256 + l16;
    const float* wrow = Wih + (522 + j)*261 + 256;
    wnT[0] = 0.1f*wrow[0]; wnT[1] = 0.1f*wrow[1]; wnT[2] = 0.1f*wrow[2];
    wnT[3] = 0.1f*wrow[3]; wnT[4] = wrow[4];
    bhhnT = bhh[522 + j];
    #pragma unroll
    for (int r = 0; r < 4; ++r) {
      const float* gb = gxb + (m0 + r)*783;
      gxrT[r] = gb[j]; gxzT[r] = gb[261 + j]; gxnT[r] = gb[522 + j];
    }
  }
  // ---- anti-remat pin for loop-invariant update state ----
  #pragma unroll
  for (int G = 0; G < 2; ++G) {
    #pragma unroll
    for (int k = 0; k < 5; ++k) asm volatile("" : "+v"(wn[G][k]));
    asm volatile("" : "+v"(bhhn[G]));
    #pragma unroll
    for (int r = 0; r < 4; ++r) {
      asm volatile("" : "+v"(gxr[G][r]));
      asm volatile("" : "+v"(gxz[G][r]));
      asm volatile("" : "+v"(gxn[G][r]));
    }
  }
  #pragma unroll
  for (int k = 0; k < 5; ++k) asm volatile("" : "+v"(wnT[k]));
  asm volatile("" : "+v"(bhhnT));
  #pragma unroll
  for (int r = 0; r < 4; ++r) {
    asm volatile("" : "+v"(gxrT[r]));
    asm volatile("" : "+v"(gxzT[r]));
    asm volatile("" : "+v"(gxnT[r]));
  }

  // prologue: zero A2 (both buffers), stage noise to LDS
  for (int i = tid; i < 2*16*296; i += 512) ((unsigned char*)A2)[i] = 0;
  for (int i = tid; i < 1600; i += 512) {
    const int t = i >> 4, m = (i >> 2) & 3, ii = i & 3;
    ns[i] = noise[(t*128 + m0 + m)*4 + ii];
  }
  __syncthreads();
  if (tid < 20) {   // t=0 noise/time cols (time_0 = 0)
    const int m = tid/5, i = tid - (tid/5)*5;
    float v = (i < 4) ? noise[(m0 + m)*4 + i]*0.1f : 0.0f;
    A2[0][m*296 + 261 + i] = pv_fp8(4.0f*v);
  }
  __syncthreads();

  const float inv32 = 1.0f/32.0f;
  for (int t = 0; t < 100; ++t) {
    const int cur = t & 1, nxt = cur ^ 1;
    f32x4 acc[7];
    #pragma unroll
    for (int s = 0; s < 7; ++s) acc[s] = (f32x4){0,0,0,0};
    #pragma unroll
    for (int c = 0; c < 9; ++c) {
      const long a = *(const long*)(&A2[cur][l16*296 + c*32 + quad*8]);
      #pragma unroll
      for (int s = 0; s < 7; ++s)
        if (s < 6 || hasTail)
          acc[s] = __builtin_amdgcn_mfma_f32_16x16x32_fp8_fp8(a, bfr[s][c], acc[s], 0, 0, 0);
    }
    if (hasTail && quad == 0) {
      #pragma unroll
      for (int r = 0; r < 4; ++r)
        DsT[wv][r][l16] = acc[6][r];
    }
    __syncthreads();   // barrier A: DsT visible

    if (up) {
      const float tv = (float)t * (1.0f/99.0f);
      float4 ne[4];
      #pragma unroll
      for (int r = 0; r < 4; ++r)
        ne[r] = *(const float4*)(&ns[t*16 + r*4]);
      #pragma unroll
      for (int G = 0; G < 2; ++G) {
        const int j = (wv*2 + G)*16 + l16;
        #pragma unroll
        for (int r = 0; r < 4; ++r) {
          float Dr = acc[G*3 + 0][r]*inv32 + gxr[G][r];
          float Dz = acc[G*3 + 1][r]*inv32 + gxz[G][r];
          float Dn = acc[G*3 + 2][r]*inv32;
          float nterm = ne[r].x*wn[G][0] + ne[r].y*wn[G][1] + ne[r].z*wn[G][2]
                      + ne[r].w*wn[G][3] + tv*wn[G][4];
          float r_ = pv_sigm(Dr);
          float z_ = pv_sigm(Dz);
          float n_ = pv_tanh(gxn[G][r] + nterm + r_*(Dn + bhhn[G]));
          hu[G][r] = (1.0f - z_)*n_ + z_*hu[G][r];
          hseq[(t*128 + m0 + r)*261 + j] = hu[G][r];
          A2[nxt][r*296 + j] = pv_fp8_fast(4.0f*hu[G][r]);
        }
      }
      if (upT) {
        const int j = 256 + l16;
        #pragma unroll
        for (int r = 0; r < 4; ++r) {
          float Dr = DsT[0][r][l16]*inv32 + gxrT[r];
          float Dz = DsT[1][r][l16]*inv32 + gxzT[r];
          float Dn = DsT[2][r][l16]*inv32;
          float nterm = ne[r].x*wnT[0] + ne[r].y*wnT[1] + ne[r].z*wnT[2]
                      + ne[r].w*wnT[3] + tv*wnT[4];
          float r_ = pv_sigm(Dr);
          float z_ = pv_sigm(Dz);
          float n_ = pv_tanh(gxnT[r] + nterm + r_*(Dn + bhhnT));
          hTl[r] = (1.0f - z_)*n_ + z_*hTl[r];
          hseq[(t*128 + m0 + r)*261 + j] = hTl[r];
          A2[nxt][r*296 + j] = pv_fp8_fast(4.0f*hTl[r]);
        }
      }
    }
    // noise/time cols for t+1 (idle quad2/3 lanes of wave 1)
    if (t < 99 && wv == 1 && lane >= 32 && lane < 52) {
      const int k = lane - 32;
      const int m = k/5, i = k - (k/5)*5;
      float v = (i < 4) ? ns[(t+1)*16 + m*4 + i]*0.1f
                        : (t+1)*(1.0f/99.0f);
      A2[nxt][m*296 + 261 + i] = pv_fp8(4.0f*v);
    }
    __syncthreads();   // barrier B: A2[nxt] complete
  }
}

// ---------------------------------------------------------------------------
// pv_frames: unchanged.
// ---------------------------------------------------------------------------
__global__ __launch_bounds__(256) void pv_frames(
    const float* hseq, const float* W1, const float* b1,
    const float* W2, const float* b2, float* out)
{
  __shared__ __align__(16) float h16[16*264];
  __shared__ unsigned w1p[64*133];
  __shared__ float f1s[16*66];
  __shared__ float w2s[576];
  const int tid = threadIdx.x;
  const int r0 = blockIdx.x * 16;    // rows rt = t*128 + b
  for (int i = tid; i < 16*264; i += 256) {
    int r = i / 264, k = i - r*264;
    h16[i] = (k < 261) ? hseq[(r0 + r)*261 + k] : 0.0f;
  }
  for (int i = tid; i < 64*131; i += 256) {
    int c = i/131, kp = i - (i/131)*131;
    int k = kp*2;
    float a0 = W1[c*261 + k];
    float a1 = (k + 1 < 261) ? W1[c*261 + k + 1] : 0.0f;
    w1p[c*133 + kp] = pv_pack2(a0, a1);
  }
  for (int i = tid; i < 576; i += 256) w2s[i] = W2[i];
  __syncthreads();
  #pragma unroll
  for (int e = 0; e < 4; ++e) {
    const int el = tid + e*256;
    const int r = el >> 6, c = el & 63;
    float s = b1[c];
    const unsigned* wp = w1p + c*133;
    const float* hr = h16 + r*264;
    for (int kp = 0; kp < 131; ++kp) {
      unsigned w = wp[kp];
      s += pv_lo(w)*hr[2*kp] + pv_hi(w)*hr[2*kp + 1];
    }
    f1s[r*66 + c] = fmaxf(s, 0.2f*s);
  }
  __syncthreads();
  if (tid < 144) {
    const int r = tid/9, oc = tid - (tid/9)*9;
    float s = b2[oc];
    const float* fr = f1s + r*66;
    const float* w = w2s + oc*64;
    #pragma unroll 8
    for (int k = 0; k < 64; ++k) s += fr[k]*w[k];
    const int rt = r0 + r;
    const int tt = rt >> 7, bb = rt & 127;
    out[bb*900 + tt*9 + oc] = pv_sigm(s);
  }
}

// ---------------------------------------------------------------------------
extern "C" __attribute__((visibility("default")))
void kernel_launch(void* const* d_in, const int* in_sizes, int n_in,
                   void* d_out, int out_size, void* d_ws, size_t ws_size,
                   hipStream_t stream)
{
  (void)in_sizes; (void)n_in; (void)out_size;
  const float* input_data = (const float*)d_in[0];
  const float* eps        = (const float*)d_in[1];
  const float* noise_eps  = (const float*)d_in[2];
  const float* proj_W     = (const float*)d_in[3];
  const float* proj_b     = (const float*)d_in[4];
  const float* lstm_Wih   = (const float*)d_in[5];
  const float* lstm_Whh   = (const float*)d_in[6];
  const float* lstm_bih   = (const float*)d_in[7];
  const float* lstm_bhh   = (const float*)d_in[8];
  const float* mu_W       = (const float*)d_in[9];
  const float* mu_b       = (const float*)d_in[10];
  const float* lv_W       = (const float*)d_in[11];
  const float* lv_b       = (const float*)d_in[12];
  const float* fcin_W     = (const float*)d_in[13];
  const float* fcin_b     = (const float*)d_in[14];
  const float* gru_Wih    = (const float*)d_in[15];
  const float* gru_Whh    = (const float*)d_in[16];
  const float* gru_bih    = (const float*)d_in[17];
  const float* gru_bhh    = (const float*)d_in[18];
  const float* jf_W1      = (const float*)d_in[19];
  const float* jf_b1      = (const float*)d_in[20];
  const float* jf_W2      = (const float*)d_in[21];
  const float* jf_b2      = (const float*)d_in[22];

  char* w = (char*)d_ws;
  float*              xg   = (float*)(w);                          // 26,214,400 B
  unsigned long long* wfp8 = (unsigned long long*)(w + 26214400);  //    235,008 B
  float*              hT   = (float*)(w + 26449408);               //     65,536 B
  float*              xvec = (float*)(w + 26514944);               //    131,072 B
  float*              gxb  = (float*)(w + 26646016);               //    400,896 B
  float*              hseq = (float*)(w + 27046912);               // 13,363,200 B (end 40,410,112)
  unsigned*           wihb = (unsigned*)(w + 40410112);            //  4,194,304 B (end 44,604,416)
  float*              outf = (float*)d_out;

  const int use_split = (ws_size >= (size_t)44604416ull);

  pv_prep_gru8<<<115, 256, 0, stream>>>(gru_Whh, gru_Wih, wfp8);
  if (use_split) {
    pv_prep_wih<<<1024, 256, 0, stream>>>(lstm_Wih, wihb);
    pv_gemm3<<<100, 512, 0, stream>>>(input_data, proj_W, proj_b, wihb,
                                      lstm_bih, lstm_bhh, xg);
  } else {
    pv_gemm<<<dim3(100, 4), 256, 0, stream>>>(input_data, proj_W, proj_b,
                                              lstm_Wih, lstm_bih, lstm_bhh, xg);
  }
  pv_lstm2<<<8, 512, 0, stream>>>(xg, lstm_Whh, hT);
  pv_head<<<128, 64, 0, stream>>>(hT, eps, mu_W, mu_b, lv_W, lv_b,
                                  fcin_W, fcin_b, xvec, outf);
  pv_gxbase<<<dim3(16, 4), 256, 0, stream>>>(xvec, gru_Wih, gru_bih, gru_bhh, gxb);
  pv_gru3<<<32, 512, 0, stream>>>(gxb, wfp8, gru_Wih, gru_bhh, noise_eps, hseq);
  pv_frames<<<800, 256, 0, stream>>>(hseq, jf_W1, jf_b1, jf_W2, jf_b2, outf);
}